// Round 2
// baseline (180.995 us; speedup 1.0000x reference)
//
#include <hip/hip_runtime.h>

#define B_DIM 4096
#define L_DIM 2048
#define TPB   256
#define EPT   8                      // L_DIM / TPB
#define NWAVE (TPB / 64)
#define TAU_INV 1.0526315789473684f  // 1/0.95

// One block per row. Writes:
//   partials[row]         = sum_j log(t_j/tau) * q_j   (softmax-weighted)
//   partials[B_DIM + row] = sum_j sum_{views} (y*logp + (1-y)*log1mp)
__global__ __launch_bounds__(TPB) void milecut_row_kernel(
    const float* __restrict__ trunc,
    const float* __restrict__ view1,
    const float* __restrict__ view2,
    const float* __restrict__ view3,
    const float* __restrict__ labels,
    float* __restrict__ partials)
{
    const int row  = blockIdx.x;
    const int t    = threadIdx.x;
    const int lane = t & 63;
    const int wave = t >> 6;
    const size_t rowOff = (size_t)row * L_DIM;

    // ---- preload EVERYTHING up front: 10 independent float4 loads ----
    // (latency overlaps the scan arithmetic below)
    const float4* y4 = (const float4*)(labels + rowOff) + t * 2;
    const float4* t4 = (const float4*)(trunc  + rowOff) + t * 2;
    const float4* p1 = (const float4*)(view1  + rowOff) + t * 2;
    const float4* p2 = (const float4*)(view2  + rowOff) + t * 2;
    const float4* p3 = (const float4*)(view3  + rowOff) + t * 2;
    float4 ya = y4[0], yb = y4[1];
    float4 ta = t4[0], tb = t4[1];
    float4 v1a = p1[0], v1b = p1[1];
    float4 v2a = p2[0], v2b = p2[1];
    float4 v3a = p3[0], v3b = p3[1];

    float y[EPT]  = {ya.x, ya.y, ya.z, ya.w, yb.x, yb.y, yb.z, yb.w};

    float lsum = 0.f;
    #pragma unroll
    for (int k = 0; k < EPT; ++k) lsum += y[k];

    // ---- inclusive scan of per-thread sums across the 64-lane wave ----
    float v = lsum;
    #pragma unroll
    for (int off = 1; off < 64; off <<= 1) {
        float n = __shfl_up(v, off, 64);
        if (lane >= off) v += n;
    }
    float waveTotal = __shfl(v, 63, 64);

    // ---- combine the 4 wave totals through LDS (exact: small integers) ----
    __shared__ float wtot[NWAVE];
    __shared__ float red[NWAVE][3];
    if (lane == 63) wtot[wave] = waveTotal;
    __syncthreads();
    float wavePrefix = 0.f, total = 0.f;
    #pragma unroll
    for (int w = 0; w < NWAVE; ++w) {
        float wt = wtot[w];
        if (w < wave) wavePrefix += wt;
        total += wt;
    }
    // exclusive prefix for this thread's first element
    float run = wavePrefix + (v - lsum);

    // ---- r = where(cum>0, 2*cum/(k+total), 0); e = exp(r/tau) directly
    //      (r/tau <= 1.06 so no max-subtraction needed) ----
    float x[EPT];
    float esum = 0.f;
    #pragma unroll
    for (int k = 0; k < EPT; ++k) {
        run += y[k];                               // inclusive cumsum
        float denom = (float)(t * EPT + k + 1) + total;
        float r = (run > 0.f) ? (2.f * run) / denom : 0.f;
        x[k] = __expf(r * TAU_INV);
        esum += x[k];
    }

    // ---- trunc: sum log(t/tau) * e ----
    float tv[EPT] = {ta.x, ta.y, ta.z, ta.w, tb.x, tb.y, tb.z, tb.w};
    float wtr = 0.f;
    #pragma unroll
    for (int k = 0; k < EPT; ++k) wtr += __logf(tv[k] * TAU_INV) * x[k];

    // ---- BCE for 3 views. y in {0,1} exactly:
    //      y*logp + (1-y)*log1mp == log(y ? p : 1-p), clamped at -100 ----
    float pv1[EPT] = {v1a.x, v1a.y, v1a.z, v1a.w, v1b.x, v1b.y, v1b.z, v1b.w};
    float pv2[EPT] = {v2a.x, v2a.y, v2a.z, v2a.w, v2b.x, v2b.y, v2b.z, v2b.w};
    float pv3[EPT] = {v3a.x, v3a.y, v3a.z, v3a.w, v3b.x, v3b.y, v3b.z, v3b.w};
    float bce = 0.f;
    #pragma unroll
    for (int k = 0; k < EPT; ++k) {
        bool pos = (y[k] > 0.5f);
        float s1 = pos ? pv1[k] : (1.0f - pv1[k]);
        float s2 = pos ? pv2[k] : (1.0f - pv2[k]);
        float s3 = pos ? pv3[k] : (1.0f - pv3[k]);
        bce += fmaxf(__logf(s1), -100.0f);
        bce += fmaxf(__logf(s2), -100.0f);
        bce += fmaxf(__logf(s3), -100.0f);
    }

    // ---- wave butterfly reduce of (esum, wtr, bce) ----
    #pragma unroll
    for (int off = 32; off > 0; off >>= 1) {
        esum += __shfl_down(esum, off, 64);
        wtr  += __shfl_down(wtr,  off, 64);
        bce  += __shfl_down(bce,  off, 64);
    }
    if (lane == 0) { red[wave][0] = esum; red[wave][1] = wtr; red[wave][2] = bce; }
    __syncthreads();

    if (t == 0) {
        float es = 0.f, wt = 0.f, bc = 0.f;
        #pragma unroll
        for (int w = 0; w < NWAVE; ++w) {
            es += red[w][0]; wt += red[w][1]; bc += red[w][2];
        }
        partials[row]         = wt / es;   // sum_j log(t/tau)*q_j for this row
        partials[B_DIM + row] = bc;        // combined raw bce sum for this row
    }
}

__global__ __launch_bounds__(TPB) void milecut_final_kernel(
    const float* __restrict__ partials, float* __restrict__ out)
{
    const int t = threadIdx.x;
    float st = 0.f, sb = 0.f;
    for (int i = t; i < B_DIM; i += TPB) {
        st += partials[i];
        sb += partials[B_DIM + i];
    }
    // wave reduce
    #pragma unroll
    for (int off = 32; off > 0; off >>= 1) {
        st += __shfl_down(st, off, 64);
        sb += __shfl_down(sb, off, 64);
    }
    __shared__ float s1[NWAVE];
    __shared__ float s2[NWAVE];
    const int lane = t & 63, wave = t >> 6;
    if (lane == 0) { s1[wave] = st; s2[wave] = sb; }
    __syncthreads();
    if (t == 0) {
        double St = 0.0, Sb = 0.0;
        #pragma unroll
        for (int w = 0; w < NWAVE; ++w) { St += (double)s1[w]; Sb += (double)s2[w]; }
        // trunc_loss = -sum(log_out * q) / B
        double trunc_loss = -St / (double)B_DIM;
        // v1+v2+v3 = -(S1+S2+S3) / (B*L) / B
        double vsum = -Sb / ((double)B_DIM * (double)L_DIM * (double)B_DIM);
        out[0] = (float)(0.5 * trunc_loss + 0.5 * vsum);
    }
}

extern "C" void kernel_launch(void* const* d_in, const int* in_sizes, int n_in,
                              void* d_out, int out_size, void* d_ws, size_t ws_size,
                              hipStream_t stream) {
    const float* trunc  = (const float*)d_in[0];
    const float* v1     = (const float*)d_in[1];
    const float* v2     = (const float*)d_in[2];
    const float* v3     = (const float*)d_in[3];
    const float* labels = (const float*)d_in[4];

    float* partials = (float*)d_ws;  // needs 2*B_DIM*4 = 32 KB

    milecut_row_kernel<<<B_DIM, TPB, 0, stream>>>(trunc, v1, v2, v3, labels, partials);
    milecut_final_kernel<<<1, TPB, 0, stream>>>(partials, (float*)d_out);
}